// Round 11
// baseline (349.957 us; speedup 1.0000x reference)
//
#include <hip/hip_runtime.h>
#include <stdint.h>

#define T_TOK 2048
#define HDIM 1024
#define NEXP 8
#define IDIM 3584
#define MAXTILE 40

// ws layout (bytes)
#define WS_CNT   0
#define WS_BASE  64
#define WS_TE    128
#define WS_TM    384
#define WS_NT    640
#define WS_TOK   704
#define WS_GW    (WS_TOK + NEXP * T_TOK * 4)
#define WS_XB    (WS_GW + NEXP * T_TOK * 4)
#define WS_G     (WS_XB + T_TOK * HDIM * 2)
// g: 4096 pairs x IDIM bf16 = 29,360,128 B ; total ~33.7 MB

typedef __attribute__((ext_vector_type(8))) short bf16x8;
typedef __attribute__((ext_vector_type(16))) float f32x16;

__device__ __forceinline__ unsigned short f2bf(float f) {
    union { float f; unsigned int u; } a; a.f = f;
    unsigned int u = a.u;
    return (unsigned short)((u + 0x7fffu + ((u >> 16) & 1u)) >> 16);
}

// packed fp32->bf16 RNE, 2 elems / instr
__device__ __forceinline__ unsigned int cvt_pk_bf16(float lo, float hi) {
    unsigned int r;
    asm("v_cvt_pk_bf16_f32 %0, %1, %2" : "=v"(r) : "v"(lo), "v"(hi));
    return r;
}

__device__ __forceinline__ uint4 pack8(const float4 a, const float4 b) {
    uint4 r;
    r.x = cvt_pk_bf16(a.x, a.y);
    r.y = cvt_pk_bf16(a.z, a.w);
    r.z = cvt_pk_bf16(b.x, b.y);
    r.w = cvt_pk_bf16(b.z, b.w);
    return r;
}

// async global->LDS, 16B per lane; dest = wave-uniform base + lane*16
__device__ __forceinline__ void gload16(const void* gsrc, void* ldst) {
    __builtin_amdgcn_global_load_lds(
        (const __attribute__((address_space(1))) unsigned int*)gsrc,
        (__attribute__((address_space(3))) unsigned int*)ldst, 16, 0, 0);
}

#define SB() __builtin_amdgcn_sched_barrier(0)

__global__ __launch_bounds__(256) void xcvt_kernel(
    const float* __restrict__ x, unsigned short* __restrict__ xb)
{
    int i = (blockIdx.x * 256 + threadIdx.x) * 8;
    float4 a = *(const float4*)(x + i);
    float4 b = *(const float4*)(x + i + 4);
    *(uint4*)(xb + i) = pack8(a, b);
}

__global__ __launch_bounds__(256) void router_kernel(
    const float* __restrict__ x, const float* __restrict__ gate_w,
    int* __restrict__ cnt, int* __restrict__ tok, float* __restrict__ gw)
{
    int t = blockIdx.x * 4 + (threadIdx.x >> 6);
    int lane = threadIdx.x & 63;
    if (t >= T_TOK) return;
    const float* xr = x + (size_t)t * HDIM;
    float part[NEXP];
#pragma unroll
    for (int e = 0; e < NEXP; e++) part[e] = 0.f;
    for (int h = lane; h < HDIM; h += 64) {
        float xv = xr[h];
#pragma unroll
        for (int e = 0; e < NEXP; e++) part[e] += xv * gate_w[e * HDIM + h];
    }
#pragma unroll
    for (int e = 0; e < NEXP; e++) {
        float v = part[e];
#pragma unroll
        for (int o = 32; o > 0; o >>= 1) v += __shfl_xor(v, o);
        part[e] = v;
    }
    if (lane == 0) {
        int i0 = 0; float v0 = part[0];
#pragma unroll
        for (int e = 1; e < NEXP; e++) if (part[e] > v0) { v0 = part[e]; i0 = e; }
        int i1 = -1; float v1 = -3.4e38f;
#pragma unroll
        for (int e = 0; e < NEXP; e++) if (e != i0 && part[e] > v1) { v1 = part[e]; i1 = e; }
        float d = __expf(v1 - v0);
        float w1v = d / (1.f + d);
        float w0v = 1.f - w1v;
        int p0 = atomicAdd(&cnt[i0], 1);
        tok[i0 * T_TOK + p0] = t; gw[i0 * T_TOK + p0] = w0v;
        int p1 = atomicAdd(&cnt[i1], 1);
        tok[i1 * T_TOK + p1] = t; gw[i1 * T_TOK + p1] = w1v;
    }
}

__global__ void scan_kernel(const int* __restrict__ cnt, int* __restrict__ base,
                            int* __restrict__ tileE, int* __restrict__ tileM,
                            int* __restrict__ ntot)
{
    if (threadIdx.x == 0) {
        int s = 0, nt = 0;
        for (int e = 0; e < NEXP; e++) {
            base[e] = s; s += cnt[e];
            for (int m0 = 0; m0 < cnt[e]; m0 += 128) {
                tileE[nt] = e; tileM[nt] = m0; nt++;
            }
        }
        *ntot = nt;
    }
}

// ---------------- ffn1: g = silu(x@w1^T) * (x@w3^T) --------------------
// Tile 128 tok x 64 i, BK=64. Fully double-buffered step buffer
// S[b] = { xs 16K @+0 | w1 8K @+16384 | w3 8K @+24576 }, b in {0,1}.
// One s_barrier per K-step. Bottom wait vmcnt(8): at that point outstanding
// is provably [G(st+1)=4, W(st+2)=8] because the ds_write of W(st+1) carries
// a compiler-inserted register-dependency wait that drains everything older.
__global__ __launch_bounds__(256, 2) void ffn1_mfma(
    const unsigned short* __restrict__ xb,
    const float* __restrict__ w1,
    const float* __restrict__ w3,
    const int* __restrict__ cnt, const int* __restrict__ base,
    const int* __restrict__ tok,
    const int* __restrict__ tileE, const int* __restrict__ tileM,
    const int* __restrict__ ntot,
    unsigned short* __restrict__ g)
{
    const int ti = blockIdx.y;
    if (ti >= *ntot) return;
    const int e = tileE[ti];
    const int m0 = tileM[ti];
    const int cntE = cnt[e];
    const int i0 = blockIdx.x * 64;
    const int tid = threadIdx.x;
    const int lane = tid & 63;
    const int wid = tid >> 6;

    __shared__ __align__(16) unsigned char lds[65536];

    const int xrr = (lane >> 3);
    const unsigned xoff = ((((unsigned)(lane & 7)) * 16) ^ (((unsigned)xrr) << 4)) >> 1;
    const unsigned short* xsrc[4];
#pragma unroll
    for (int i = 0; i < 4; i++) {
        int row = wid * 32 + i * 8 + xrr;
        int t = tok[e * T_TOK + min(m0 + row, cntE - 1)];
        xsrc[i] = xb + (size_t)t * HDIM + xoff;
    }

    const int rw = tid >> 2;                     // 0..63 (i-row)
    const int kq = tid & 3;                      // 16-float chunk
    const unsigned swzW = ((unsigned)(rw & 7)) << 4;
    const unsigned wd0 = (((unsigned)kq) * 32) ^ swzW;
    const unsigned wd1 = (((unsigned)kq) * 32 + 16) ^ swzW;
    const float* w1e = w1 + ((size_t)e * IDIM + i0 + rw) * HDIM + kq * 16;
    const float* w3e = w3 + ((size_t)e * IDIM + i0 + rw) * HDIM + kq * 16;

    f32x16 acc1[2], acc3[2];
#pragma unroll
    for (int a = 0; a < 2; a++)
#pragma unroll
        for (int r = 0; r < 16; r++) { acc1[a][r] = 0.f; acc3[a][r] = 0.f; }

    const int wr = wid >> 1;
    const int wc = wid & 1;
    const unsigned lrow = (unsigned)(lane & 31);
    const unsigned lswz = (lrow & 7) << 4;
    const unsigned hi16 = (unsigned)((lane >> 5) * 16);
    const unsigned aOff  = (wr * 64 + lrow) * 128;
    const unsigned b1Off = 16384u + (wc * 32 + lrow) * 128;
    const unsigned b3Off = 24576u + (wc * 32 + lrow) * 128;
    const unsigned xdst = (unsigned)(wid * 32) * 128;

    float4 wva[4], wvb[4];

    // ---- prologue: populate S0 fully; preload W(1) regs; one full sync.
#pragma unroll
    for (int i = 0; i < 4; i++)
        gload16(xsrc[i], lds + xdst + (unsigned)(i * 8) * 128);
#pragma unroll
    for (int i = 0; i < 4; i++) {
        wva[i] = *(const float4*)(w1e + i * 4);
        wvb[i] = *(const float4*)(w3e + i * 4);
    }
    asm volatile("s_waitcnt vmcnt(0)" ::: "memory");
    *(uint4*)(lds + 16384u + rw * 128 + wd0) = pack8(wva[0], wva[1]);
    *(uint4*)(lds + 16384u + rw * 128 + wd1) = pack8(wva[2], wva[3]);
    *(uint4*)(lds + 24576u + rw * 128 + wd0) = pack8(wvb[0], wvb[1]);
    *(uint4*)(lds + 24576u + rw * 128 + wd1) = pack8(wvb[2], wvb[3]);
#pragma unroll
    for (int i = 0; i < 4; i++) {
        wva[i] = *(const float4*)(w1e + 64 + i * 4);
        wvb[i] = *(const float4*)(w3e + 64 + i * 4);
    }
    __syncthreads();   // full drain once; S0 ready, W(1) in regs (landed)

    for (int st = 0; st < HDIM / 64; st++) {
        const unsigned cb = (unsigned)(st & 1) * 32768u;
        const unsigned nb = cb ^ 32768u;
        SB();
        // issue G(st+1) -> S[nb].xs (clamped tail duplicates are race-free)
        const int kg = min((st + 1) * 64, HDIM - 64);
#pragma unroll
        for (int i = 0; i < 4; i++)
            gload16(xsrc[i] + kg, lds + nb + xdst + (unsigned)(i * 8) * 128);
        SB();
        // ds_write S[nb].w from W(st+1) regs (implicit vmcnt wait drains older)
        *(uint4*)(lds + nb + 16384u + rw * 128 + wd0) = pack8(wva[0], wva[1]);
        *(uint4*)(lds + nb + 16384u + rw * 128 + wd1) = pack8(wva[2], wva[3]);
        *(uint4*)(lds + nb + 24576u + rw * 128 + wd0) = pack8(wvb[0], wvb[1]);
        *(uint4*)(lds + nb + 24576u + rw * 128 + wd1) = pack8(wvb[2], wvb[3]);
        SB();
        // load W(st+2) regs (clamped)
        const int kw = min((st + 2) * 64, HDIM - 64);
#pragma unroll
        for (int i = 0; i < 4; i++) {
            wva[i] = *(const float4*)(w1e + kw + i * 4);
            wvb[i] = *(const float4*)(w3e + kw + i * 4);
        }
        SB();
        // MFMA on S[cb]
#pragma unroll
        for (int s = 0; s < 4; s++) {
            const unsigned off = (((unsigned)(s * 32)) + hi16) ^ lswz;
            bf16x8 a0 = *(const bf16x8*)(lds + cb + aOff + off);
            bf16x8 a1 = *(const bf16x8*)(lds + cb + aOff + 32 * 128 + off);
            bf16x8 p0 = *(const bf16x8*)(lds + cb + b1Off + off);
            bf16x8 q0 = *(const bf16x8*)(lds + cb + b3Off + off);
            acc1[0] = __builtin_amdgcn_mfma_f32_32x32x16_bf16(a0, p0, acc1[0], 0, 0, 0);
            acc1[1] = __builtin_amdgcn_mfma_f32_32x32x16_bf16(a1, p0, acc1[1], 0, 0, 0);
            acc3[0] = __builtin_amdgcn_mfma_f32_32x32x16_bf16(a0, q0, acc3[0], 0, 0, 0);
            acc3[1] = __builtin_amdgcn_mfma_f32_32x32x16_bf16(a1, q0, acc3[1], 0, 0, 0);
        }
        // bottom: drain G(st+1) (outstanding = [G 4, W 8]) + my LDS ops
        asm volatile("s_waitcnt vmcnt(8) lgkmcnt(0)" ::: "memory");
        SB();
        __builtin_amdgcn_s_barrier();
    }
    asm volatile("s_waitcnt vmcnt(0)" ::: "memory");

    const int pbase = base[e] + m0;
    const int colI = i0 + wc * 32 + (int)lrow;
    const int rb4 = 4 * (lane >> 5);
#pragma unroll
    for (int ma = 0; ma < 2; ma++) {
#pragma unroll
        for (int r = 0; r < 16; r++) {
            int row = (r & 3) + 8 * (r >> 2) + rb4;
            int m = wr * 64 + ma * 32 + row;
            if (m0 + m < cntE) {
                float h1 = acc1[ma][r], h3 = acc3[ma][r];
                float v = (h1 / (1.f + __expf(-h1))) * h3;
                g[(size_t)(pbase + m) * IDIM + colI] = f2bf(v);
            }
        }
    }
}

// ---------------- ffn2: out += gate * (g @ w2^T) -----------------------
// Tile 128 pairs x 64 h, split-K x4. S[b] = { gs 16K @+0 | w2 8K @+16384 },
// bases 0 / 24576. Same single-barrier pipeline; bottom wait vmcnt(4).
__global__ __launch_bounds__(256, 3) void ffn2_mfma(
    const unsigned short* __restrict__ g,
    const float* __restrict__ w2,
    const int* __restrict__ cnt, const int* __restrict__ base,
    const int* __restrict__ tok, const float* __restrict__ gw,
    const int* __restrict__ tileE, const int* __restrict__ tileM,
    const int* __restrict__ ntot,
    float* __restrict__ out)
{
    const int ti = blockIdx.y;
    if (ti >= *ntot) return;
    const int e = tileE[ti];
    const int m0 = tileM[ti];
    const int cntE = cnt[e];
    const int pane = blockIdx.x;               // 0..63
    const int h0 = (pane & 15) * 64;
    const int ks = pane >> 4;                  // 0..3
    const int tid = threadIdx.x;
    const int lane = tid & 63;
    const int wid = tid >> 6;

    __shared__ __align__(16) unsigned char lds[49152];

    const int kbeg = ks * (IDIM / 4);          // 896-elem split, 14 K-steps
    const int KSP = IDIM / 4;

    const int xrr = (lane >> 3);
    const unsigned xoff = ((((unsigned)(lane & 7)) * 16) ^ (((unsigned)xrr) << 4)) >> 1;
    const unsigned short* gsrc[4];
    const int be = base[e];
#pragma unroll
    for (int i = 0; i < 4; i++) {
        int row = wid * 32 + i * 8 + xrr;
        int grow = be + min(m0 + row, cntE - 1);
        gsrc[i] = g + (size_t)grow * IDIM + kbeg + xoff;
    }

    const int rw = tid >> 2;                   // 0..63 (h-row)
    const int kq = tid & 3;
    const unsigned swzW = ((unsigned)(rw & 7)) << 4;
    const unsigned wd0 = (((unsigned)kq) * 32) ^ swzW;
    const unsigned wd1 = (((unsigned)kq) * 32 + 16) ^ swzW;
    const float* w2e = w2 + ((size_t)e * HDIM + h0 + rw) * IDIM + kbeg + kq * 16;

    f32x16 acc[2];
#pragma unroll
    for (int a = 0; a < 2; a++)
#pragma unroll
        for (int r = 0; r < 16; r++) acc[a][r] = 0.f;

    const int wr = wid >> 1;
    const int wc = wid & 1;
    const unsigned lrow = (unsigned)(lane & 31);
    const unsigned lswz = (lrow & 7) << 4;
    const unsigned hi16 = (unsigned)((lane >> 5) * 16);
    const unsigned aOff = (wr * 64 + lrow) * 128;
    const unsigned bOff = 16384u + (wc * 32 + lrow) * 128;
    const unsigned xdst = (unsigned)(wid * 32) * 128;

    float4 wv[4];

    // prologue
#pragma unroll
    for (int i = 0; i < 4; i++)
        gload16(gsrc[i], lds + xdst + (unsigned)(i * 8) * 128);
#pragma unroll
    for (int i = 0; i < 4; i++)
        wv[i] = *(const float4*)(w2e + i * 4);
    asm volatile("s_waitcnt vmcnt(0)" ::: "memory");
    *(uint4*)(lds + 16384u + rw * 128 + wd0) = pack8(wv[0], wv[1]);
    *(uint4*)(lds + 16384u + rw * 128 + wd1) = pack8(wv[2], wv[3]);
#pragma unroll
    for (int i = 0; i < 4; i++)
        wv[i] = *(const float4*)(w2e + 64 + i * 4);
    __syncthreads();

    const int NST = KSP / 64;                  // 14
    for (int st = 0; st < NST; st++) {
        const unsigned cb = (unsigned)(st & 1) * 24576u;
        const unsigned nb = cb ^ 24576u;
        SB();
        const int kg = min((st + 1) * 64, KSP - 64);
#pragma unroll
        for (int i = 0; i < 4; i++)
            gload16(gsrc[i] + kg, lds + nb + xdst + (unsigned)(i * 8) * 128);
        SB();
        *(uint4*)(lds + nb + 16384u + rw * 128 + wd0) = pack8(wv[0], wv[1]);
        *(uint4*)(lds + nb + 16384u + rw * 128 + wd1) = pack8(wv[2], wv[3]);
        SB();
        const int kw = min((st + 2) * 64, KSP - 64);
#pragma unroll
        for (int i = 0; i < 4; i++)
            wv[i] = *(const float4*)(w2e + kw + i * 4);
        SB();
#pragma unroll
        for (int s = 0; s < 4; s++) {
            const unsigned off = (((unsigned)(s * 32)) + hi16) ^ lswz;
            bf16x8 a0 = *(const bf16x8*)(lds + cb + aOff + off);
            bf16x8 a1 = *(const bf16x8*)(lds + cb + aOff + 32 * 128 + off);
            bf16x8 b0 = *(const bf16x8*)(lds + cb + bOff + off);
            acc[0] = __builtin_amdgcn_mfma_f32_32x32x16_bf16(a0, b0, acc[0], 0, 0, 0);
            acc[1] = __builtin_amdgcn_mfma_f32_32x32x16_bf16(a1, b0, acc[1], 0, 0, 0);
        }
        asm volatile("s_waitcnt vmcnt(4) lgkmcnt(0)" ::: "memory");
        SB();
        __builtin_amdgcn_s_barrier();
    }
    asm volatile("s_waitcnt vmcnt(0)" ::: "memory");

    const int rb4 = 4 * (lane >> 5);
    const int hcol = h0 + wc * 32 + (int)lrow;
#pragma unroll
    for (int ma = 0; ma < 2; ma++) {
#pragma unroll
        for (int r = 0; r < 16; r++) {
            int row = (r & 3) + 8 * (r >> 2) + rb4;
            int m = wr * 64 + ma * 32 + row;
            if (m0 + m < cntE) {
                int idx = e * T_TOK + m0 + m;
                int t = tok[idx];
                float wgt = gw[idx];
                atomicAdd(out + (size_t)t * HDIM + hcol, wgt * acc[ma][r]);
            }
        }
    }
}

extern "C" void kernel_launch(void* const* d_in, const int* in_sizes, int n_in,
                              void* d_out, int out_size, void* d_ws, size_t ws_size,
                              hipStream_t stream) {
    const float* x      = (const float*)d_in[0];
    const float* gate_w = (const float*)d_in[1];
    const float* w1     = (const float*)d_in[2];
    const float* w2     = (const float*)d_in[3];
    const float* w3     = (const float*)d_in[4];
    float* out = (float*)d_out;
    char* ws = (char*)d_ws;
    int* cnt   = (int*)(ws + WS_CNT);
    int* base  = (int*)(ws + WS_BASE);
    int* tileE = (int*)(ws + WS_TE);
    int* tileM = (int*)(ws + WS_TM);
    int* ntot  = (int*)(ws + WS_NT);
    int* tok   = (int*)(ws + WS_TOK);
    float* gw  = (float*)(ws + WS_GW);
    unsigned short* xb = (unsigned short*)(ws + WS_XB);
    unsigned short* g  = (unsigned short*)(ws + WS_G);

    hipMemsetAsync(cnt, 0, 64, stream);
    hipMemsetAsync(d_out, 0, (size_t)out_size * sizeof(float), stream);

    xcvt_kernel<<<T_TOK * HDIM / (256 * 8), 256, 0, stream>>>(x, xb);
    router_kernel<<<T_TOK / 4, 256, 0, stream>>>(x, gate_w, cnt, tok, gw);
    scan_kernel<<<1, 64, 0, stream>>>(cnt, base, tileE, tileM, ntot);
    ffn1_mfma<<<dim3(IDIM / 64, MAXTILE), 256, 0, stream>>>(xb, w1, w3, cnt, base, tok, tileE, tileM, ntot, g);
    ffn2_mfma<<<dim3(64, MAXTILE), 256, 0, stream>>>(g, w2, cnt, base, tok, gw, tileE, tileM, ntot, out);
}

// Round 13
// 330.839 us; speedup vs baseline: 1.0578x; 1.0578x over previous
//
#include <hip/hip_runtime.h>
#include <stdint.h>

#define T_TOK 2048
#define HDIM 1024
#define NEXP 8
#define IDIM 3584
#define MAXTILE 40

// ws layout (bytes)
#define WS_CNT   0
#define WS_BASE  64
#define WS_TE    128
#define WS_TM    384
#define WS_NT    640
#define WS_TOK   704
#define WS_GW    (WS_TOK + NEXP * T_TOK * 4)
#define WS_XB    (WS_GW + NEXP * T_TOK * 4)
#define WS_G     (WS_XB + T_TOK * HDIM * 2)
// g: 4096 pairs x IDIM bf16 = 29,360,128 B ; total ~33.7 MB

typedef __attribute__((ext_vector_type(8))) short bf16x8;
typedef __attribute__((ext_vector_type(16))) float f32x16;

__device__ __forceinline__ unsigned short f2bf(float f) {
    union { float f; unsigned int u; } a; a.f = f;
    unsigned int u = a.u;
    return (unsigned short)((u + 0x7fffu + ((u >> 16) & 1u)) >> 16);
}

// packed fp32->bf16 RNE, 2 elems / instr
__device__ __forceinline__ unsigned int cvt_pk_bf16(float lo, float hi) {
    unsigned int r;
    asm("v_cvt_pk_bf16_f32 %0, %1, %2" : "=v"(r) : "v"(lo), "v"(hi));
    return r;
}

__device__ __forceinline__ uint4 pack8(const float4 a, const float4 b) {
    uint4 r;
    r.x = cvt_pk_bf16(a.x, a.y);
    r.y = cvt_pk_bf16(a.z, a.w);
    r.z = cvt_pk_bf16(b.x, b.y);
    r.w = cvt_pk_bf16(b.z, b.w);
    return r;
}

// async global->LDS, 16B per lane; dest = wave-uniform base + lane*16
__device__ __forceinline__ void gload16(const void* gsrc, void* ldst) {
    __builtin_amdgcn_global_load_lds(
        (const __attribute__((address_space(1))) unsigned int*)gsrc,
        (__attribute__((address_space(3))) unsigned int*)ldst, 16, 0, 0);
}

__global__ __launch_bounds__(256) void xcvt_kernel(
    const float* __restrict__ x, unsigned short* __restrict__ xb)
{
    int i = (blockIdx.x * 256 + threadIdx.x) * 8;
    float4 a = *(const float4*)(x + i);
    float4 b = *(const float4*)(x + i + 4);
    *(uint4*)(xb + i) = pack8(a, b);
}

__global__ __launch_bounds__(256) void router_kernel(
    const float* __restrict__ x, const float* __restrict__ gate_w,
    int* __restrict__ cnt, int* __restrict__ tok, float* __restrict__ gw)
{
    int t = blockIdx.x * 4 + (threadIdx.x >> 6);
    int lane = threadIdx.x & 63;
    if (t >= T_TOK) return;
    const float* xr = x + (size_t)t * HDIM;
    float part[NEXP];
#pragma unroll
    for (int e = 0; e < NEXP; e++) part[e] = 0.f;
    for (int h = lane; h < HDIM; h += 64) {
        float xv = xr[h];
#pragma unroll
        for (int e = 0; e < NEXP; e++) part[e] += xv * gate_w[e * HDIM + h];
    }
#pragma unroll
    for (int e = 0; e < NEXP; e++) {
        float v = part[e];
#pragma unroll
        for (int o = 32; o > 0; o >>= 1) v += __shfl_xor(v, o);
        part[e] = v;
    }
    if (lane == 0) {
        int i0 = 0; float v0 = part[0];
#pragma unroll
        for (int e = 1; e < NEXP; e++) if (part[e] > v0) { v0 = part[e]; i0 = e; }
        int i1 = -1; float v1 = -3.4e38f;
#pragma unroll
        for (int e = 0; e < NEXP; e++) if (e != i0 && part[e] > v1) { v1 = part[e]; i1 = e; }
        float d = __expf(v1 - v0);
        float w1v = d / (1.f + d);
        float w0v = 1.f - w1v;
        int p0 = atomicAdd(&cnt[i0], 1);
        tok[i0 * T_TOK + p0] = t; gw[i0 * T_TOK + p0] = w0v;
        int p1 = atomicAdd(&cnt[i1], 1);
        tok[i1 * T_TOK + p1] = t; gw[i1 * T_TOK + p1] = w1v;
    }
}

__global__ void scan_kernel(const int* __restrict__ cnt, int* __restrict__ base,
                            int* __restrict__ tileE, int* __restrict__ tileM,
                            int* __restrict__ ntot)
{
    if (threadIdx.x == 0) {
        int s = 0, nt = 0;
        for (int e = 0; e < NEXP; e++) {
            base[e] = s; s += cnt[e];
            for (int m0 = 0; m0 < cnt[e]; m0 += 128) {
                tileE[nt] = e; tileM[nt] = m0; nt++;
            }
        }
        *ntot = nt;
    }
}

// ffn1: g = silu(x@w1^T) * (x@w3^T). Tile 128 tok x 64 i, BK=32, 4 waves.
// High-TLP config: LDS 24 KB (xs dbuf 2x8K + w1 4K + w3 4K); (256,5) ->
// ~102 VGPR budget, 5 blocks/CU (5 independent barrier groups).
__global__ __launch_bounds__(256, 5) void ffn1_mfma(
    const unsigned short* __restrict__ xb,
    const float* __restrict__ w1,
    const float* __restrict__ w3,
    const int* __restrict__ cnt, const int* __restrict__ base,
    const int* __restrict__ tok,
    const int* __restrict__ tileE, const int* __restrict__ tileM,
    const int* __restrict__ ntot,
    unsigned short* __restrict__ g)
{
    const int ti = blockIdx.y;
    if (ti >= *ntot) return;
    const int e = tileE[ti];
    const int m0 = tileM[ti];
    const int cntE = cnt[e];
    const int i0 = blockIdx.x * 64;
    const int tid = threadIdx.x;
    const int lane = tid & 63;
    const int wid = tid >> 6;

    __shared__ __align__(16) unsigned char lds[24576];
    // xs[0] @0 (8K), xs[1] @8192 (8K), w1s @16384 (4K), w3s @20480 (4K)

    // ---- x gather sources (swizzle pre-folded into per-lane global source)
    const int xrr = (lane >> 2);                 // 0..15 row-in-instr
    const unsigned xoff = ((((unsigned)(lane & 3)) * 16) ^ (((unsigned)(xrr & 3)) << 4)) >> 1;
    const unsigned short* xsrc[2];
#pragma unroll
    for (int i = 0; i < 2; i++) {
        int row = wid * 32 + i * 16 + xrr;
        int t = tok[e * T_TOK + min(m0 + row, cntE - 1)];
        xsrc[i] = xb + (size_t)t * HDIM + xoff;
    }

    // ---- weight staging (reg -> cvt -> LDS); rows 64B wide (32 bf16)
    const int rw = tid >> 2;                     // 0..63 (i-row)
    const int kq = tid & 3;                      // 8-float chunk
    const unsigned wd = (((unsigned)kq) * 16) ^ (((unsigned)(rw & 3)) << 4);
    const float* w1e = w1 + ((size_t)e * IDIM + i0 + rw) * HDIM + kq * 8;
    const float* w3e = w3 + ((size_t)e * IDIM + i0 + rw) * HDIM + kq * 8;

    f32x16 acc1[2], acc3[2];
#pragma unroll
    for (int a = 0; a < 2; a++)
#pragma unroll
        for (int r = 0; r < 16; r++) { acc1[a][r] = 0.f; acc3[a][r] = 0.f; }

    const int wr = wid >> 1;                     // token half (0/1)
    const int wc = wid & 1;                      // i half (0/1) -> 32 cols
    const unsigned lrow = (unsigned)(lane & 31);
    const unsigned lswz = (lrow & 3) << 4;
    const unsigned hi16 = (unsigned)((lane >> 5) * 16);
    const unsigned aOff  = (wr * 64 + lrow) * 64;
    const unsigned b1Off = 16384u + (wc * 32 + lrow) * 64;
    const unsigned b3Off = 20480u + (wc * 32 + lrow) * 64;
    const unsigned xdst = (unsigned)(wid * 2048);

    float4 wva[2], wvb[2];

    // prologue: k=0 loads
#pragma unroll
    for (int i = 0; i < 2; i++)
        gload16(xsrc[i], lds + xdst + (unsigned)(i * 1024));
    wva[0] = *(const float4*)(w1e);
    wva[1] = *(const float4*)(w1e + 4);
    wvb[0] = *(const float4*)(w3e);
    wvb[1] = *(const float4*)(w3e + 4);

    const int NST = HDIM / 32;                   // 32 steps
    for (int st = 0; st < NST; st++) {
        const unsigned xsb = (unsigned)(st & 1) * 8192u;
        const int k0 = st * 32;
        __syncthreads();   // xs[cur] landed (vmcnt drain); prev W reads done
        *(uint4*)(lds + 16384u + rw * 64 + wd) = pack8(wva[0], wva[1]);
        *(uint4*)(lds + 20480u + rw * 64 + wd) = pack8(wvb[0], wvb[1]);
        __syncthreads();   // weight writes visible

        // issue NEXT K-step's loads — fly under the MFMAs + next barrier
        if (k0 + 32 < HDIM) {
            const int kn = k0 + 32;
            const unsigned xnb = xsb ^ 8192u;
#pragma unroll
            for (int i = 0; i < 2; i++)
                gload16(xsrc[i] + kn, lds + xnb + xdst + (unsigned)(i * 1024));
            wva[0] = *(const float4*)(w1e + kn);
            wva[1] = *(const float4*)(w1e + kn + 4);
            wvb[0] = *(const float4*)(w3e + kn);
            wvb[1] = *(const float4*)(w3e + kn + 4);
        }

#pragma unroll
        for (int s = 0; s < 2; s++) {
            const unsigned off = (((unsigned)(s * 32)) + hi16) ^ lswz;
            bf16x8 a0 = *(const bf16x8*)(lds + xsb + aOff + off);
            bf16x8 a1 = *(const bf16x8*)(lds + xsb + aOff + 32 * 64 + off);
            bf16x8 b1 = *(const bf16x8*)(lds + b1Off + off);
            bf16x8 b3 = *(const bf16x8*)(lds + b3Off + off);
            acc1[0] = __builtin_amdgcn_mfma_f32_32x32x16_bf16(a0, b1, acc1[0], 0, 0, 0);
            acc1[1] = __builtin_amdgcn_mfma_f32_32x32x16_bf16(a1, b1, acc1[1], 0, 0, 0);
            acc3[0] = __builtin_amdgcn_mfma_f32_32x32x16_bf16(a0, b3, acc3[0], 0, 0, 0);
            acc3[1] = __builtin_amdgcn_mfma_f32_32x32x16_bf16(a1, b3, acc3[1], 0, 0, 0);
        }
    }

    const int pbase = base[e] + m0;
    const int colI = i0 + wc * 32 + (int)lrow;
    const int rb4 = 4 * (lane >> 5);
#pragma unroll
    for (int ma = 0; ma < 2; ma++) {
#pragma unroll
        for (int r = 0; r < 16; r++) {
            int row = (r & 3) + 8 * (r >> 2) + rb4;
            int m = wr * 64 + ma * 32 + row;
            if (m0 + m < cntE) {
                float h1 = acc1[ma][r], h3 = acc3[ma][r];
                float v = (h1 / (1.f + __expf(-h1))) * h3;
                g[(size_t)(pbase + m) * IDIM + colI] = f2bf(v);
            }
        }
    }
}

// ffn2: out[t,h] += gate * (g @ w2^T). Tile 128 pairs x 64 h, split-K x4,
// gs double-buffered via global_load_lds. LDS 40 KB -> 4 blocks/CU. (R8 config)
__global__ __launch_bounds__(256, 4) void ffn2_mfma(
    const unsigned short* __restrict__ g,
    const float* __restrict__ w2,
    const int* __restrict__ cnt, const int* __restrict__ base,
    const int* __restrict__ tok, const float* __restrict__ gw,
    const int* __restrict__ tileE, const int* __restrict__ tileM,
    const int* __restrict__ ntot,
    float* __restrict__ out)
{
    const int ti = blockIdx.y;
    if (ti >= *ntot) return;
    const int e = tileE[ti];
    const int m0 = tileM[ti];
    const int cntE = cnt[e];
    const int pane = blockIdx.x;               // 0..63
    const int h0 = (pane & 15) * 64;
    const int ks = pane >> 4;                  // 0..3
    const int tid = threadIdx.x;
    const int lane = tid & 63;
    const int wid = tid >> 6;

    __shared__ __align__(16) unsigned char lds[40960];
    // gs[0] @0 (16K), gs[1] @16384 (16K), w2s @32768 (8K)

    const int kbeg = ks * (IDIM / 4);          // 896-elem split, 14 K-steps

    const int xrr = (lane >> 3);
    const unsigned xoff = ((((unsigned)(lane & 7)) * 16) ^ (((unsigned)xrr) << 4)) >> 1;
    const unsigned short* gsrc[4];
    const int be = base[e];
#pragma unroll
    for (int i = 0; i < 4; i++) {
        int row = wid * 32 + i * 8 + xrr;
        int grow = be + min(m0 + row, cntE - 1);
        gsrc[i] = g + (size_t)grow * IDIM + kbeg + xoff;
    }

    const int rw = tid >> 2;                   // 0..63 (h-row)
    const int kq = tid & 3;
    const unsigned swzW = ((unsigned)(rw & 7)) << 4;
    const unsigned wd0 = (((unsigned)kq) * 32) ^ swzW;
    const unsigned wd1 = (((unsigned)kq) * 32 + 16) ^ swzW;
    const float* w2e = w2 + ((size_t)e * HDIM + h0 + rw) * IDIM + kbeg + kq * 16;

    f32x16 acc[2];
#pragma unroll
    for (int a = 0; a < 2; a++)
#pragma unroll
        for (int r = 0; r < 16; r++) acc[a][r] = 0.f;

    const int wr = wid >> 1;
    const int wc = wid & 1;
    const unsigned lrow = (unsigned)(lane & 31);
    const unsigned lswz = (lrow & 7) << 4;
    const unsigned hi16 = (unsigned)((lane >> 5) * 16);
    const unsigned aRow = (wr * 64 + lrow) * 128;
    const unsigned bRow = 32768u + (wc * 32 + lrow) * 128;

    float4 wv[4];
#pragma unroll
    for (int i = 0; i < 4; i++)
        gload16(gsrc[i], lds + (wid * 32 + i * 8) * 128);
#pragma unroll
    for (int i = 0; i < 4; i++)
        wv[i] = *(const float4*)(w2e + i * 4);

    const int NST = (IDIM / 4) / 64;           // 14
    for (int st = 0; st < NST; st++) {
        const unsigned xsb = (unsigned)(st & 1) * 16384u;
        const int k0 = st * 64;
        __syncthreads();
        *(uint4*)(lds + 32768u + rw * 128 + wd0) = pack8(wv[0], wv[1]);
        *(uint4*)(lds + 32768u + rw * 128 + wd1) = pack8(wv[2], wv[3]);
        __syncthreads();

        if (st + 1 < NST) {
            const unsigned xnb = xsb ^ 16384u;
#pragma unroll
            for (int i = 0; i < 4; i++)
                gload16(gsrc[i] + k0 + 64, lds + xnb + (wid * 32 + i * 8) * 128);
#pragma unroll
            for (int i = 0; i < 4; i++)
                wv[i] = *(const float4*)(w2e + k0 + 64 + i * 4);
        }

#pragma unroll
        for (int s = 0; s < 4; s++) {
            const unsigned off = (((unsigned)(s * 32)) + hi16) ^ lswz;
            bf16x8 a0 = *(const bf16x8*)(lds + xsb + aRow + off);
            bf16x8 a1 = *(const bf16x8*)(lds + xsb + aRow + 32 * 128 + off);
            bf16x8 b0 = *(const bf16x8*)(lds + bRow + off);
            acc[0] = __builtin_amdgcn_mfma_f32_32x32x16_bf16(a0, b0, acc[0], 0, 0, 0);
            acc[1] = __builtin_amdgcn_mfma_f32_32x32x16_bf16(a1, b0, acc[1], 0, 0, 0);
        }
    }

    const int rb4 = 4 * (lane >> 5);
    const int hcol = h0 + wc * 32 + (int)lrow;
#pragma unroll
    for (int ma = 0; ma < 2; ma++) {
#pragma unroll
        for (int r = 0; r < 16; r++) {
            int row = (r & 3) + 8 * (r >> 2) + rb4;
            int m = wr * 64 + ma * 32 + row;
            if (m0 + m < cntE) {
                int idx = e * T_TOK + m0 + m;
                int t = tok[idx];
                float wgt = gw[idx];
                atomicAdd(out + (size_t)t * HDIM + hcol, wgt * acc[ma][r]);
            }
        }
    }
}

extern "C" void kernel_launch(void* const* d_in, const int* in_sizes, int n_in,
                              void* d_out, int out_size, void* d_ws, size_t ws_size,
                              hipStream_t stream) {
    const float* x      = (const float*)d_in[0];
    const float* gate_w = (const float*)d_in[1];
    const float* w1     = (const float*)d_in[2];
    const float* w2     = (const float*)d_in[3];
    const float* w3     = (const float*)d_in[4];
    float* out = (float*)d_out;
    char* ws = (char*)d_ws;
    int* cnt   = (int*)(ws + WS_CNT);
    int* base  = (int*)(ws + WS_BASE);
    int* tileE = (int*)(ws + WS_TE);
    int* tileM = (int*)(ws + WS_TM);
    int* ntot  = (int*)(ws + WS_NT);
    int* tok   = (int*)(ws + WS_TOK);
    float* gw  = (float*)(ws + WS_GW);
    unsigned short* xb = (unsigned short*)(ws + WS_XB);
    unsigned short* g  = (unsigned short*)(ws + WS_G);

    hipMemsetAsync(cnt, 0, 64, stream);
    hipMemsetAsync(d_out, 0, (size_t)out_size * sizeof(float), stream);

    xcvt_kernel<<<T_TOK * HDIM / (256 * 8), 256, 0, stream>>>(x, xb);
    router_kernel<<<T_TOK / 4, 256, 0, stream>>>(x, gate_w, cnt, tok, gw);
    scan_kernel<<<1, 64, 0, stream>>>(cnt, base, tileE, tileM, ntot);
    ffn1_mfma<<<dim3(IDIM / 64, MAXTILE), 256, 0, stream>>>(xb, w1, w3, cnt, base, tok, tileE, tileM, ntot, g);
    ffn2_mfma<<<dim3(64, MAXTILE), 256, 0, stream>>>(g, w2, cnt, base, tok, gw, tileE, tileM, ntot, out);
}

// Round 14
// 327.842 us; speedup vs baseline: 1.0675x; 1.0091x over previous
//
#include <hip/hip_runtime.h>
#include <stdint.h>

#define T_TOK 2048
#define HDIM 1024
#define NEXP 8
#define IDIM 3584
#define MAXTILE 40

// ws layout (bytes)
#define WS_CNT   0
#define WS_BASE  64
#define WS_TE    128
#define WS_TM    384
#define WS_NT    640
#define WS_TOK   704
#define WS_GW    (WS_TOK + NEXP * T_TOK * 4)
#define WS_XB    (WS_GW + NEXP * T_TOK * 4)
#define WS_G     (WS_XB + T_TOK * HDIM * 2)
// g: 4096 pairs x IDIM bf16 = 29,360,128 B ; total ~33.7 MB

typedef __attribute__((ext_vector_type(8))) short bf16x8;
typedef __attribute__((ext_vector_type(16))) float f32x16;

__device__ __forceinline__ unsigned short f2bf(float f) {
    union { float f; unsigned int u; } a; a.f = f;
    unsigned int u = a.u;
    return (unsigned short)((u + 0x7fffu + ((u >> 16) & 1u)) >> 16);
}

// packed fp32->bf16 RNE, 2 elems / instr
__device__ __forceinline__ unsigned int cvt_pk_bf16(float lo, float hi) {
    unsigned int r;
    asm("v_cvt_pk_bf16_f32 %0, %1, %2" : "=v"(r) : "v"(lo), "v"(hi));
    return r;
}

__device__ __forceinline__ uint4 pack8(const float4 a, const float4 b) {
    uint4 r;
    r.x = cvt_pk_bf16(a.x, a.y);
    r.y = cvt_pk_bf16(a.z, a.w);
    r.z = cvt_pk_bf16(b.x, b.y);
    r.w = cvt_pk_bf16(b.z, b.w);
    return r;
}

// async global->LDS, 16B per lane; dest = wave-uniform base + lane*16
__device__ __forceinline__ void gload16(const void* gsrc, void* ldst) {
    __builtin_amdgcn_global_load_lds(
        (const __attribute__((address_space(1))) unsigned int*)gsrc,
        (__attribute__((address_space(3))) unsigned int*)ldst, 16, 0, 0);
}

__global__ __launch_bounds__(256) void xcvt_kernel(
    const float* __restrict__ x, unsigned short* __restrict__ xb)
{
    int i = (blockIdx.x * 256 + threadIdx.x) * 8;
    float4 a = *(const float4*)(x + i);
    float4 b = *(const float4*)(x + i + 4);
    *(uint4*)(xb + i) = pack8(a, b);
}

__global__ __launch_bounds__(256) void router_kernel(
    const float* __restrict__ x, const float* __restrict__ gate_w,
    int* __restrict__ cnt, int* __restrict__ tok, float* __restrict__ gw)
{
    int t = blockIdx.x * 4 + (threadIdx.x >> 6);
    int lane = threadIdx.x & 63;
    if (t >= T_TOK) return;
    const float* xr = x + (size_t)t * HDIM;
    float part[NEXP];
#pragma unroll
    for (int e = 0; e < NEXP; e++) part[e] = 0.f;
    for (int h = lane; h < HDIM; h += 64) {
        float xv = xr[h];
#pragma unroll
        for (int e = 0; e < NEXP; e++) part[e] += xv * gate_w[e * HDIM + h];
    }
#pragma unroll
    for (int e = 0; e < NEXP; e++) {
        float v = part[e];
#pragma unroll
        for (int o = 32; o > 0; o >>= 1) v += __shfl_xor(v, o);
        part[e] = v;
    }
    if (lane == 0) {
        int i0 = 0; float v0 = part[0];
#pragma unroll
        for (int e = 1; e < NEXP; e++) if (part[e] > v0) { v0 = part[e]; i0 = e; }
        int i1 = -1; float v1 = -3.4e38f;
#pragma unroll
        for (int e = 0; e < NEXP; e++) if (e != i0 && part[e] > v1) { v1 = part[e]; i1 = e; }
        float d = __expf(v1 - v0);
        float w1v = d / (1.f + d);
        float w0v = 1.f - w1v;
        int p0 = atomicAdd(&cnt[i0], 1);
        tok[i0 * T_TOK + p0] = t; gw[i0 * T_TOK + p0] = w0v;
        int p1 = atomicAdd(&cnt[i1], 1);
        tok[i1 * T_TOK + p1] = t; gw[i1 * T_TOK + p1] = w1v;
    }
}

__global__ void scan_kernel(const int* __restrict__ cnt, int* __restrict__ base,
                            int* __restrict__ tileE, int* __restrict__ tileM,
                            int* __restrict__ ntot)
{
    if (threadIdx.x == 0) {
        int s = 0, nt = 0;
        for (int e = 0; e < NEXP; e++) {
            base[e] = s; s += cnt[e];
            for (int m0 = 0; m0 < cnt[e]; m0 += 128) {
                tileE[nt] = e; tileM[nt] = m0; nt++;
            }
        }
        *ntot = nt;
    }
}

// ffn1: g = silu(x@w1^T) * (x@w3^T). Tile 128 tok x 128 i, BK=64, 4 waves 2x2.
// Per wave 64tok x 64i for BOTH tensors: 6 LDS frag-reads -> 8 MFMA per s-iter.
// xs double-buffered via global_load_lds; weights reg-staged fp32->bf16.
__global__ __launch_bounds__(256, 2) void ffn1_mfma(
    const unsigned short* __restrict__ xb,
    const float* __restrict__ w1,
    const float* __restrict__ w3,
    const int* __restrict__ cnt, const int* __restrict__ base,
    const int* __restrict__ tok,
    const int* __restrict__ tileE, const int* __restrict__ tileM,
    const int* __restrict__ ntot,
    unsigned short* __restrict__ g)
{
    const int ti = blockIdx.y;
    if (ti >= *ntot) return;
    const int e = tileE[ti];
    const int m0 = tileM[ti];
    const int cntE = cnt[e];
    const int i0 = blockIdx.x * 128;
    const int tid = threadIdx.x;
    const int lane = tid & 63;
    const int wid = tid >> 6;

    __shared__ __align__(16) unsigned char lds[65536];
    // XS0 @0 (16K), XS1 @16384 (16K), W1S @32768 (16K), W3S @49152 (16K)

    const int xrr = (lane >> 3);
    const unsigned xoff = ((((unsigned)(lane & 7)) * 16) ^ (((unsigned)xrr) << 4)) >> 1;
    const unsigned short* xsrc[4];
#pragma unroll
    for (int i = 0; i < 4; i++) {
        int row = wid * 32 + i * 8 + xrr;
        int t = tok[e * T_TOK + min(m0 + row, cntE - 1)];
        xsrc[i] = xb + (size_t)t * HDIM + xoff;
    }

    // weight staging: thread (rw,kq) covers i-rows rw and rw+64, both tensors
    const int rw = tid >> 2;                     // 0..63
    const int kq = tid & 3;                      // 16-float chunk
    const unsigned swzW = ((unsigned)(rw & 7)) << 4;
    const unsigned wd0 = (((unsigned)kq) * 32) ^ swzW;
    const unsigned wd1 = (((unsigned)kq) * 32 + 16) ^ swzW;
    const float* w1e = w1 + ((size_t)e * IDIM + i0 + rw) * HDIM + kq * 16;
    const float* w3e = w3 + ((size_t)e * IDIM + i0 + rw) * HDIM + kq * 16;
    const size_t rhalf = (size_t)64 * HDIM;      // +64 rows

    f32x16 acc1[2][2], acc3[2][2];
#pragma unroll
    for (int a = 0; a < 2; a++)
#pragma unroll
        for (int b = 0; b < 2; b++)
#pragma unroll
            for (int r = 0; r < 16; r++) { acc1[a][b][r] = 0.f; acc3[a][b][r] = 0.f; }

    const int wr = wid >> 1;                     // token half
    const int wc = wid & 1;                      // i half (64 cols)
    const unsigned lrow = (unsigned)(lane & 31);
    const unsigned lswz = (lrow & 7) << 4;
    const unsigned hi16 = (unsigned)((lane >> 5) * 16);
    const unsigned aOff  = (wr * 64 + lrow) * 128;
    const unsigned b1Off = 32768u + (wc * 64 + lrow) * 128;
    const unsigned b3Off = 49152u + (wc * 64 + lrow) * 128;
    const unsigned xdst = (unsigned)(wid * 32) * 128;

    float4 wva[2][4], wvb[2][4];                 // [row-half][chunk]

    // prologue: k=0
#pragma unroll
    for (int i = 0; i < 4; i++)
        gload16(xsrc[i], lds + xdst + (unsigned)(i * 8) * 128);
#pragma unroll
    for (int h = 0; h < 2; h++)
#pragma unroll
        for (int i = 0; i < 4; i++) {
            wva[h][i] = *(const float4*)(w1e + h * rhalf + i * 4);
            wvb[h][i] = *(const float4*)(w3e + h * rhalf + i * 4);
        }

    for (int st = 0; st < HDIM / 64; st++) {
        const unsigned xsb = (unsigned)(st & 1) * 16384u;
        const int k0 = st * 64;
        __syncthreads();   // xs[cur] landed; prev weight reads done
#pragma unroll
        for (int h = 0; h < 2; h++) {
            *(uint4*)(lds + 32768u + (rw + h * 64) * 128 + wd0) = pack8(wva[h][0], wva[h][1]);
            *(uint4*)(lds + 32768u + (rw + h * 64) * 128 + wd1) = pack8(wva[h][2], wva[h][3]);
            *(uint4*)(lds + 49152u + (rw + h * 64) * 128 + wd0) = pack8(wvb[h][0], wvb[h][1]);
            *(uint4*)(lds + 49152u + (rw + h * 64) * 128 + wd1) = pack8(wvb[h][2], wvb[h][3]);
        }
        __syncthreads();   // weight writes visible

        if (k0 + 64 < HDIM) {
            const int kn = k0 + 64;
            const unsigned xnb = xsb ^ 16384u;
#pragma unroll
            for (int i = 0; i < 4; i++)
                gload16(xsrc[i] + kn, lds + xnb + xdst + (unsigned)(i * 8) * 128);
#pragma unroll
            for (int h = 0; h < 2; h++)
#pragma unroll
                for (int i = 0; i < 4; i++) {
                    wva[h][i] = *(const float4*)(w1e + h * rhalf + kn + i * 4);
                    wvb[h][i] = *(const float4*)(w3e + h * rhalf + kn + i * 4);
                }
        }

#pragma unroll
        for (int s = 0; s < 4; s++) {
            const unsigned off = (((unsigned)(s * 32)) + hi16) ^ lswz;
            bf16x8 a0 = *(const bf16x8*)(lds + xsb + aOff + off);
            bf16x8 a1 = *(const bf16x8*)(lds + xsb + aOff + 32 * 128 + off);
            bf16x8 p0 = *(const bf16x8*)(lds + b1Off + off);
            bf16x8 p1 = *(const bf16x8*)(lds + b1Off + 32 * 128 + off);
            bf16x8 q0 = *(const bf16x8*)(lds + b3Off + off);
            bf16x8 q1 = *(const bf16x8*)(lds + b3Off + 32 * 128 + off);
            acc1[0][0] = __builtin_amdgcn_mfma_f32_32x32x16_bf16(a0, p0, acc1[0][0], 0, 0, 0);
            acc1[0][1] = __builtin_amdgcn_mfma_f32_32x32x16_bf16(a0, p1, acc1[0][1], 0, 0, 0);
            acc1[1][0] = __builtin_amdgcn_mfma_f32_32x32x16_bf16(a1, p0, acc1[1][0], 0, 0, 0);
            acc1[1][1] = __builtin_amdgcn_mfma_f32_32x32x16_bf16(a1, p1, acc1[1][1], 0, 0, 0);
            acc3[0][0] = __builtin_amdgcn_mfma_f32_32x32x16_bf16(a0, q0, acc3[0][0], 0, 0, 0);
            acc3[0][1] = __builtin_amdgcn_mfma_f32_32x32x16_bf16(a0, q1, acc3[0][1], 0, 0, 0);
            acc3[1][0] = __builtin_amdgcn_mfma_f32_32x32x16_bf16(a1, q0, acc3[1][0], 0, 0, 0);
            acc3[1][1] = __builtin_amdgcn_mfma_f32_32x32x16_bf16(a1, q1, acc3[1][1], 0, 0, 0);
        }
    }

    const int pbase = base[e] + m0;
    const int rb4 = 4 * (lane >> 5);
#pragma unroll
    for (int ma = 0; ma < 2; ma++) {
#pragma unroll
        for (int r = 0; r < 16; r++) {
            int row = (r & 3) + 8 * (r >> 2) + rb4;
            int m = wr * 64 + ma * 32 + row;
            if (m0 + m < cntE) {
                unsigned short* grow = g + (size_t)(pbase + m) * IDIM + i0 + wc * 64 + lrow;
#pragma unroll
                for (int nb = 0; nb < 2; nb++) {
                    float h1 = acc1[ma][nb][r], h3 = acc3[ma][nb][r];
                    float v = (h1 / (1.f + __expf(-h1))) * h3;
                    grow[nb * 32] = f2bf(v);
                }
            }
        }
    }
}

// ffn2: out[t,h] += gate * (g @ w2^T). Tile 128 pairs x 128 h, split-K x4.
// 2x2 waves, 64x64 per wave: 4 frag-reads -> 4 MFMA. LDS 48 KB -> 3/CU.
__global__ __launch_bounds__(256, 3) void ffn2_mfma(
    const unsigned short* __restrict__ g,
    const float* __restrict__ w2,
    const int* __restrict__ cnt, const int* __restrict__ base,
    const int* __restrict__ tok, const float* __restrict__ gw,
    const int* __restrict__ tileE, const int* __restrict__ tileM,
    const int* __restrict__ ntot,
    float* __restrict__ out)
{
    const int ti = blockIdx.y;
    if (ti >= *ntot) return;
    const int e = tileE[ti];
    const int m0 = tileM[ti];
    const int cntE = cnt[e];
    const int pane = blockIdx.x;               // 0..31
    const int h0 = (pane & 7) * 128;
    const int ks = pane >> 3;                  // 0..3
    const int tid = threadIdx.x;
    const int lane = tid & 63;
    const int wid = tid >> 6;

    __shared__ __align__(16) unsigned char lds[49152];
    // GS0 @0 (16K), GS1 @16384 (16K), W2S @32768 (16K)

    const int kbeg = ks * (IDIM / 4);          // 896-elem split, 14 K-steps

    const int xrr = (lane >> 3);
    const unsigned xoff = ((((unsigned)(lane & 7)) * 16) ^ (((unsigned)xrr) << 4)) >> 1;
    const unsigned short* gsrc[4];
    const int be = base[e];
#pragma unroll
    for (int i = 0; i < 4; i++) {
        int row = wid * 32 + i * 8 + xrr;
        int grow = be + min(m0 + row, cntE - 1);
        gsrc[i] = g + (size_t)grow * IDIM + kbeg + xoff;
    }

    const int rw = tid >> 2;                   // 0..63 ; covers h-rows rw, rw+64
    const int kq = tid & 3;
    const unsigned swzW = ((unsigned)(rw & 7)) << 4;
    const unsigned wd0 = (((unsigned)kq) * 32) ^ swzW;
    const unsigned wd1 = (((unsigned)kq) * 32 + 16) ^ swzW;
    const float* w2e = w2 + ((size_t)e * HDIM + h0 + rw) * IDIM + kbeg + kq * 16;
    const size_t rhalf = (size_t)64 * IDIM;

    f32x16 acc[2][2];
#pragma unroll
    for (int a = 0; a < 2; a++)
#pragma unroll
        for (int b = 0; b < 2; b++)
#pragma unroll
            for (int r = 0; r < 16; r++) acc[a][b][r] = 0.f;

    const int wr = wid >> 1;
    const int wc = wid & 1;                    // h half (64 cols)
    const unsigned lrow = (unsigned)(lane & 31);
    const unsigned lswz = (lrow & 7) << 4;
    const unsigned hi16 = (unsigned)((lane >> 5) * 16);
    const unsigned aOff = (wr * 64 + lrow) * 128;
    const unsigned bOff = 32768u + (wc * 64 + lrow) * 128;
    const unsigned xdst = (unsigned)(wid * 32) * 128;

    float4 wv[2][4];

    // prologue
#pragma unroll
    for (int i = 0; i < 4; i++)
        gload16(gsrc[i], lds + xdst + (unsigned)(i * 8) * 128);
#pragma unroll
    for (int h = 0; h < 2; h++)
#pragma unroll
        for (int i = 0; i < 4; i++)
            wv[h][i] = *(const float4*)(w2e + h * rhalf + i * 4);

    const int NST = (IDIM / 4) / 64;           // 14
    for (int st = 0; st < NST; st++) {
        const unsigned xsb = (unsigned)(st & 1) * 16384u;
        const int k0 = st * 64;
        __syncthreads();
#pragma unroll
        for (int h = 0; h < 2; h++) {
            *(uint4*)(lds + 32768u + (rw + h * 64) * 128 + wd0) = pack8(wv[h][0], wv[h][1]);
            *(uint4*)(lds + 32768u + (rw + h * 64) * 128 + wd1) = pack8(wv[h][2], wv[h][3]);
        }
        __syncthreads();

        if (st + 1 < NST) {
            const int kn = k0 + 64;
            const unsigned xnb = xsb ^ 16384u;
#pragma unroll
            for (int i = 0; i < 4; i++)
                gload16(gsrc[i] + kn, lds + xnb + xdst + (unsigned)(i * 8) * 128);
#pragma unroll
            for (int h = 0; h < 2; h++)
#pragma unroll
                for (int i = 0; i < 4; i++)
                    wv[h][i] = *(const float4*)(w2e + h * rhalf + kn + i * 4);
        }

#pragma unroll
        for (int s = 0; s < 4; s++) {
            const unsigned off = (((unsigned)(s * 32)) + hi16) ^ lswz;
            bf16x8 a0 = *(const bf16x8*)(lds + xsb + aOff + off);
            bf16x8 a1 = *(const bf16x8*)(lds + xsb + aOff + 32 * 128 + off);
            bf16x8 b0 = *(const bf16x8*)(lds + bOff + off);
            bf16x8 b1 = *(const bf16x8*)(lds + bOff + 32 * 128 + off);
            acc[0][0] = __builtin_amdgcn_mfma_f32_32x32x16_bf16(a0, b0, acc[0][0], 0, 0, 0);
            acc[0][1] = __builtin_amdgcn_mfma_f32_32x32x16_bf16(a0, b1, acc[0][1], 0, 0, 0);
            acc[1][0] = __builtin_amdgcn_mfma_f32_32x32x16_bf16(a1, b0, acc[1][0], 0, 0, 0);
            acc[1][1] = __builtin_amdgcn_mfma_f32_32x32x16_bf16(a1, b1, acc[1][1], 0, 0, 0);
        }
    }

    const int rb4 = 4 * (lane >> 5);
    const int hcol = h0 + wc * 64 + (int)lrow;
#pragma unroll
    for (int ma = 0; ma < 2; ma++) {
#pragma unroll
        for (int r = 0; r < 16; r++) {
            int row = (r & 3) + 8 * (r >> 2) + rb4;
            int m = wr * 64 + ma * 32 + row;
            if (m0 + m < cntE) {
                int idx = e * T_TOK + m0 + m;
                int t = tok[idx];
                float wgt = gw[idx];
                atomicAdd(out + (size_t)t * HDIM + hcol,      wgt * acc[ma][0][r]);
                atomicAdd(out + (size_t)t * HDIM + hcol + 32, wgt * acc[ma][1][r]);
            }
        }
    }
}

extern "C" void kernel_launch(void* const* d_in, const int* in_sizes, int n_in,
                              void* d_out, int out_size, void* d_ws, size_t ws_size,
                              hipStream_t stream) {
    const float* x      = (const float*)d_in[0];
    const float* gate_w = (const float*)d_in[1];
    const float* w1     = (const float*)d_in[2];
    const float* w2     = (const float*)d_in[3];
    const float* w3     = (const float*)d_in[4];
    float* out = (float*)d_out;
    char* ws = (char*)d_ws;
    int* cnt   = (int*)(ws + WS_CNT);
    int* base  = (int*)(ws + WS_BASE);
    int* tileE = (int*)(ws + WS_TE);
    int* tileM = (int*)(ws + WS_TM);
    int* ntot  = (int*)(ws + WS_NT);
    int* tok   = (int*)(ws + WS_TOK);
    float* gw  = (float*)(ws + WS_GW);
    unsigned short* xb = (unsigned short*)(ws + WS_XB);
    unsigned short* g  = (unsigned short*)(ws + WS_G);

    hipMemsetAsync(cnt, 0, 64, stream);
    hipMemsetAsync(d_out, 0, (size_t)out_size * sizeof(float), stream);

    xcvt_kernel<<<T_TOK * HDIM / (256 * 8), 256, 0, stream>>>(x, xb);
    router_kernel<<<T_TOK / 4, 256, 0, stream>>>(x, gate_w, cnt, tok, gw);
    scan_kernel<<<1, 64, 0, stream>>>(cnt, base, tileE, tileM, ntot);
    ffn1_mfma<<<dim3(IDIM / 128, MAXTILE), 256, 0, stream>>>(xb, w1, w3, cnt, base, tok, tileE, tileM, ntot, g);
    ffn2_mfma<<<dim3(32, MAXTILE), 256, 0, stream>>>(g, w2, cnt, base, tok, gw, tileE, tileM, ntot, out);
}